// Round 3
// baseline (375.237 us; speedup 1.0000x reference)
//
#include <hip/hip_runtime.h>
#include <stdint.h>

typedef float  f32x4  __attribute__((ext_vector_type(4)));
typedef short  s16x8  __attribute__((ext_vector_type(8)));
typedef unsigned short u16;
typedef unsigned short u16x4 __attribute__((ext_vector_type(4)));

#define DEVI __device__ __forceinline__

DEVI u16 f2bf(float x) {
  uint32_t u = __float_as_uint(x);
  u += 0x7fffu + ((u >> 16) & 1u);   // RNE to bf16
  return (u16)(u >> 16);
}
DEVI float bf2f(u16 h) { return __uint_as_float(((uint32_t)h) << 16); }
DEVI float sigm(float x) { return 1.0f / (1.0f + __expf(-x)); }

// Row permutation: exp-sensitive rows (attr 2,3 of each anchor: m=2,3,87,88,172,173)
// are placed at permuted rows 0..5 so the hi/lo correction MFMA only touches frag 0.
DEVI int unperm(int pr) {
  if (pr < 6) return 85 * (pr >> 1) + 2 + (pr & 1);
  int idx = pr - 6;
  return idx + (idx < 2 ? 0 : (idx < 85 ? 2 : (idx < 168 ? 4 : 6)));
}

template<int HEAD> DEVI float anchW(int a) {
  if constexpr (HEAD == 0) return a == 0 ? 116.f/416.f : (a == 1 ? 156.f/416.f : 373.f/416.f);
  else if constexpr (HEAD == 1) return a == 0 ? 30.f/416.f : (a == 1 ? 62.f/416.f : 59.f/416.f);
  else return a == 0 ? 10.f/416.f : (a == 1 ? 16.f/416.f : 33.f/416.f);
}
template<int HEAD> DEVI float anchH(int a) {
  if constexpr (HEAD == 0) return a == 0 ? 90.f/416.f : (a == 1 ? 198.f/416.f : 326.f/416.f);
  else if constexpr (HEAD == 1) return a == 0 ? 61.f/416.f : (a == 1 ? 45.f/416.f : 119.f/416.f);
  else return a == 0 ? 13.f/416.f : (a == 1 ? 30.f/416.f : 23.f/416.f);
}

DEVI void gload_lds16(const void* g, void* l) {
  __builtin_amdgcn_global_load_lds((const __attribute__((address_space(1))) void*)g,
                                   (__attribute__((address_space(3))) void*)l, 16, 0, 0);
}

// ---------------- W pre-pack: fp32 -> bf16 (hi plane 256 rows, lo plane rows 0..15),
// row-permuted, XOR-swizzled, tiled per K-step in the exact LDS image.
// Tile layout (17408 B): [Ah 256x32 u16 swz][Al 16x32 u16 swz]
template<int K, int LOGK>
DEVI void pack_head(const float* __restrict__ Wt, u16* __restrict__ dst, int i) {
  const int pr = i >> LOGK;
  const int k  = i & (K - 1);
  float x = 0.f;
  if (pr < 255) x = Wt[(size_t)unperm(pr) * K + k];
  const u16 hi = f2bf(x);
  const int tile = k >> 5;
  const int swz  = (pr * 64 + (k & 31) * 2) ^ ((pr & 7) << 4);
  u16* tb = dst + (size_t)tile * 8704;        // 17408 B per tile
  tb[swz >> 1] = hi;
  if (pr < 16) {
    const u16 lo = f2bf(x - bf2f(hi));
    tb[8192 + (swz >> 1)] = lo;
  }
}

__global__ __launch_bounds__(256)
void pack_all(const float* __restrict__ W13, const float* __restrict__ W26,
              const float* __restrict__ W52, u16* __restrict__ p13,
              u16* __restrict__ p26, u16* __restrict__ p52) {
  const int g = (int)(blockIdx.x * 256 + threadIdx.x);
  if (g < 262144)       pack_head<1024, 10>(W13, p13, g);
  else if (g < 393216)  pack_head< 512,  9>(W26, p26, g - 262144);
  else                  pack_head< 256,  8>(W52, p52, g - 393216);
}

// ---------------- fused GEMM + decode ----------------
// Block: 256(M) x 64(N spatial), BK=32. 8 waves = 4(M) x 2(N), wave tile 64x32.
// Pass 1: Ah*Bh on everything. Correction (rows 0..15 only, waves wm==0):
// Ah*Bl + Al*Bh -> full hi/lo precision for the exp rows. 72 MFMA/block-step.
// LDS per buffer (25600 B): [Ah 16K][Al 1K][Bh 4K][Bl 4K]; double buffered = 51200 B.
template<int K, int WD, int HEAD>
DEVI void head_block(const float* __restrict__ F, const u16* __restrict__ Wp,
                     const float* __restrict__ bias, float* __restrict__ out,
                     int bidx, char* smem)
{
  constexpr int S = WD * WD;
  constexpr int NT = (S + 63) / 64;
  constexpr int NSTEP = K / 32;
  constexpr int BUF = 25600;
  constexpr int AL_OFF = 16384, BH_OFF = 17408, BL_OFF = 21504;

  const int b  = bidx / NT;
  const int s0 = (bidx - b * NT) * 64;
  const int tid  = (int)threadIdx.x;
  const int lane = tid & 63;
  const int wv   = tid >> 6;
  const int wm   = wv >> 1;
  const int wn   = wv & 1;
  const int ridx = lane & 15;
  const int kb   = (lane >> 4) << 4;          // k byte offset within row

  const float* Fb   = F + (size_t)b * K * S;
  const int    bs   = (s0 + lane < S) ? s0 + lane : S - 1;
  const float* Fcol = Fb + bs;
  const int    bwr  = (lane * 64 + wv * 8) ^ ((lane & 7) << 4);   // B write byte

  f32x4 acc[4][2];
  #pragma unroll
  for (int i = 0; i < 4; ++i)
    #pragma unroll
    for (int j = 0; j < 2; ++j)
      #pragma unroll
      for (int r = 0; r < 4; ++r) acc[i][j][r] = 0.f;

  char* buf0 = smem;
  char* buf1 = smem + BUF;

  // ---- prologue: stage t=0 into buf0 ----
  {
    const char* g = (const char*)Wp;
    gload_lds16(g + (wv*2+0)*1024 + lane*16, buf0 + (wv*2+0)*1024 + lane*16);
    gload_lds16(g + (wv*2+1)*1024 + lane*16, buf0 + (wv*2+1)*1024 + lane*16);
    if (wv == 0) gload_lds16(g + 16384 + lane*16, buf0 + 16384 + lane*16);
    float bx[4];
    #pragma unroll
    for (int j = 0; j < 4; ++j) bx[j] = Fcol[(size_t)(wv*4 + j) * S];
    u16x4 hv, lv;
    #pragma unroll
    for (int j = 0; j < 4; ++j) { u16 h = f2bf(bx[j]); hv[j] = h; lv[j] = f2bf(bx[j] - bf2f(h)); }
    *(u16x4*)(buf0 + BH_OFF + bwr) = hv;
    *(u16x4*)(buf0 + BL_OFF + bwr) = lv;
  }
  __syncthreads();

  int cur = 0;
  for (int t = 0; t < NSTEP; ++t) {
    char* lc = cur ? buf1 : buf0;
    char* ln = cur ? buf0 : buf1;
    const bool pf = (t + 1 < NSTEP);
    float bx[4];
    if (pf) {
      const char* g = (const char*)Wp + (size_t)(t + 1) * 17408;
      gload_lds16(g + (wv*2+0)*1024 + lane*16, ln + (wv*2+0)*1024 + lane*16);
      gload_lds16(g + (wv*2+1)*1024 + lane*16, ln + (wv*2+1)*1024 + lane*16);
      if (wv == 0) gload_lds16(g + 16384 + lane*16, ln + 16384 + lane*16);
      const float* fc = Fcol + (size_t)(t + 1) * 32 * S;
      #pragma unroll
      for (int j = 0; j < 4; ++j) bx[j] = fc[(size_t)(wv*4 + j) * S];
    }
    // ---- compute from current buffer ----
    s16x8 Ahf[4], Bhf[2];
    #pragma unroll
    for (int mf = 0; mf < 4; ++mf) {
      const int row = wm*64 + mf*16 + ridx;
      Ahf[mf] = *(const s16x8*)(lc + ((row*64 + kb) ^ ((row & 7) << 4)));
    }
    #pragma unroll
    for (int nf = 0; nf < 2; ++nf) {
      const int row = wn*32 + nf*16 + ridx;
      Bhf[nf] = *(const s16x8*)(lc + BH_OFF + ((row*64 + kb) ^ ((row & 7) << 4)));
    }
    #pragma unroll
    for (int mf = 0; mf < 4; ++mf)
      #pragma unroll
      for (int nf = 0; nf < 2; ++nf)
        acc[mf][nf] = __builtin_amdgcn_mfma_f32_16x16x32_bf16(Ahf[mf], Bhf[nf], acc[mf][nf], 0, 0, 0);
    if (wm == 0) {
      const s16x8 Alf = *(const s16x8*)(lc + AL_OFF + ((ridx*64 + kb) ^ ((ridx & 7) << 4)));
      #pragma unroll
      for (int nf = 0; nf < 2; ++nf) {
        const int row = wn*32 + nf*16 + ridx;
        const s16x8 Blf = *(const s16x8*)(lc + BL_OFF + ((row*64 + kb) ^ ((row & 7) << 4)));
        acc[0][nf] = __builtin_amdgcn_mfma_f32_16x16x32_bf16(Ahf[0], Blf, acc[0][nf], 0, 0, 0);
        acc[0][nf] = __builtin_amdgcn_mfma_f32_16x16x32_bf16(Alf, Bhf[nf], acc[0][nf], 0, 0, 0);
      }
    }
    if (pf) {
      u16x4 hv, lv;
      #pragma unroll
      for (int j = 0; j < 4; ++j) { u16 h = f2bf(bx[j]); hv[j] = h; lv[j] = f2bf(bx[j] - bf2f(h)); }
      *(u16x4*)(ln + BH_OFF + bwr) = hv;
      *(u16x4*)(ln + BL_OFF + bwr) = lv;
    }
    __syncthreads();
    cur ^= 1;
  }

  // ---- epilogue: decode + per-anchor LDS transpose + coalesced store ----
  float* ot = (float*)smem;                 // [64][85] floats = 21760 B
  const int vs = (S - s0) < 64 ? (S - s0) : 64;
  for (int a = 0; a < 3; ++a) {
    __syncthreads();
    #pragma unroll
    for (int mf = 0; mf < 4; ++mf) {
      #pragma unroll
      for (int nf = 0; nf < 2; ++nf) {
        const int slc = wn*32 + nf*16 + ridx;
        const int s   = s0 + slc;
        const int hh  = s / WD;
        const int ww  = s - hh * WD;
        #pragma unroll
        for (int r = 0; r < 4; ++r) {
          const int pr = wm*64 + mf*16 + ((lane >> 4) << 2) + r;
          if (pr > 254) continue;
          const int m  = unperm(pr);
          const int am = (m * 772) >> 16;
          if (am != a) continue;
          const int attr = m - 85 * am;
          const float p  = acc[mf][nf][r] + bias[m];
          float val;
          if      (attr == 0) val = ((float)ww + sigm(p)) * (1.0f / WD);
          else if (attr == 1) val = ((float)hh + sigm(p)) * (1.0f / WD);
          else if (attr == 2) val = __expf(p) * anchW<HEAD>(a);
          else if (attr == 3) val = __expf(p) * anchH<HEAD>(a);
          else                val = sigm(p);
          ot[slc * 85 + attr] = val;
        }
      }
    }
    __syncthreads();
    for (int i = tid; i < 64 * 85; i += 512) {
      const int slq = i / 85;
      if (slq < vs)
        out[((size_t)((b * 3 + a) * S) + s0 + slq) * 85 + (i - slq * 85)] = ot[i];
    }
  }
}

__global__ __launch_bounds__(512, 6)
void yolo_fused(const float* __restrict__ f13, const float* __restrict__ f26,
                const float* __restrict__ f52,
                const u16* __restrict__ p13, const float* __restrict__ b13,
                const u16* __restrict__ p26, const float* __restrict__ b26,
                const u16* __restrict__ p52, const float* __restrict__ b52,
                float* __restrict__ out)
{
  __shared__ __attribute__((aligned(16))) char smem[51200];
  const int blk = (int)blockIdx.x;
  float* out13 = out;
  float* out26 = out + 1379040;          // 32*507*85
  float* out52 = out + 6895200;          // + 32*2028*85
  if (blk < 96)        head_block<1024, 13, 0>(f13, p13, b13, out13, blk,       smem);
  else if (blk < 448)  head_block< 512, 26, 1>(f26, p26, b26, out26, blk - 96,  smem);
  else                 head_block< 256, 52, 2>(f52, p52, b52, out52, blk - 448, smem);
}

extern "C" void kernel_launch(void* const* d_in, const int* in_sizes, int n_in,
                              void* d_out, int out_size, void* d_ws, size_t ws_size,
                              hipStream_t stream) {
  (void)in_sizes; (void)n_in; (void)ws_size; (void)out_size;
  const float* f13 = (const float*)d_in[0];
  const float* f26 = (const float*)d_in[1];
  const float* f52 = (const float*)d_in[2];
  const float* W13 = (const float*)d_in[3];
  const float* b13 = (const float*)d_in[4];
  const float* W26 = (const float*)d_in[5];
  const float* b26 = (const float*)d_in[6];
  const float* W52 = (const float*)d_in[7];
  const float* b52 = (const float*)d_in[8];

  u16* p13 = (u16*)d_ws;                 // 32 tiles * 8704 u16
  u16* p26 = p13 + 32 * 8704;            // 16 tiles
  u16* p52 = p26 + 16 * 8704;            //  8 tiles   (total 974848 B)

  pack_all<<<dim3(1792), dim3(256), 0, stream>>>(W13, W26, W52, p13, p26, p52);
  yolo_fused<<<dim3(1824), dim3(512), 0, stream>>>(
      f13, f26, f52, p13, b13, p26, b26, p52, b52, (float*)d_out);
}

// Round 4
// 244.684 us; speedup vs baseline: 1.5336x; 1.5336x over previous
//
#include <hip/hip_runtime.h>
#include <stdint.h>

typedef float  f32x4  __attribute__((ext_vector_type(4)));
typedef short  s16x8  __attribute__((ext_vector_type(8)));
typedef unsigned short u16;
typedef unsigned short u16x4 __attribute__((ext_vector_type(4)));

#define DEVI __device__ __forceinline__

DEVI u16 f2bf(float x) {
  uint32_t u = __float_as_uint(x);
  u += 0x7fffu + ((u >> 16) & 1u);   // RNE to bf16
  return (u16)(u >> 16);
}
DEVI float bf2f(u16 h) { return __uint_as_float(((uint32_t)h) << 16); }
DEVI float sigm(float x) { return 1.0f / (1.0f + __expf(-x)); }

// Row permutation: exp-sensitive rows (attr 2,3 of each anchor: m=2,3,87,88,172,173)
// are placed at permuted rows 0..5 so the hi/lo correction MFMA only touches frag 0.
DEVI int unperm(int pr) {
  if (pr < 6) return 85 * (pr >> 1) + 2 + (pr & 1);
  int idx = pr - 6;
  return idx + (idx < 2 ? 0 : (idx < 85 ? 2 : (idx < 168 ? 4 : 6)));
}

template<int HEAD> DEVI float anchW(int a) {
  if constexpr (HEAD == 0) return a == 0 ? 116.f/416.f : (a == 1 ? 156.f/416.f : 373.f/416.f);
  else if constexpr (HEAD == 1) return a == 0 ? 30.f/416.f : (a == 1 ? 62.f/416.f : 59.f/416.f);
  else return a == 0 ? 10.f/416.f : (a == 1 ? 16.f/416.f : 33.f/416.f);
}
template<int HEAD> DEVI float anchH(int a) {
  if constexpr (HEAD == 0) return a == 0 ? 90.f/416.f : (a == 1 ? 198.f/416.f : 326.f/416.f);
  else if constexpr (HEAD == 1) return a == 0 ? 61.f/416.f : (a == 1 ? 45.f/416.f : 119.f/416.f);
  else return a == 0 ? 13.f/416.f : (a == 1 ? 30.f/416.f : 23.f/416.f);
}

DEVI void gload_lds16(const void* g, void* l) {
  __builtin_amdgcn_global_load_lds((const __attribute__((address_space(1))) void*)g,
                                   (__attribute__((address_space(3))) void*)l, 16, 0, 0);
}

// ---------------- W pre-pack: fp32 -> bf16 (hi plane 256 rows, lo plane rows 0..15),
// row-permuted, XOR-swizzled, tiled per K-step in the exact LDS image.
// Tile layout (17408 B): [Ah 256x32 u16 swz][Al 16x32 u16 swz]
template<int K, int LOGK>
DEVI void pack_head(const float* __restrict__ Wt, u16* __restrict__ dst, int i) {
  const int pr = i >> LOGK;
  const int k  = i & (K - 1);
  float x = 0.f;
  if (pr < 255) x = Wt[(size_t)unperm(pr) * K + k];
  const u16 hi = f2bf(x);
  const int tile = k >> 5;
  const int swz  = (pr * 64 + (k & 31) * 2) ^ ((pr & 7) << 4);
  u16* tb = dst + (size_t)tile * 8704;        // 17408 B per tile
  tb[swz >> 1] = hi;
  if (pr < 16) {
    const u16 lo = f2bf(x - bf2f(hi));
    tb[8192 + (swz >> 1)] = lo;
  }
}

__global__ __launch_bounds__(256)
void pack_all(const float* __restrict__ W13, const float* __restrict__ W26,
              const float* __restrict__ W52, u16* __restrict__ p13,
              u16* __restrict__ p26, u16* __restrict__ p52) {
  const int g = (int)(blockIdx.x * 256 + threadIdx.x);
  if (g < 262144)       pack_head<1024, 10>(W13, p13, g);
  else if (g < 393216)  pack_head< 512,  9>(W26, p26, g - 262144);
  else                  pack_head< 256,  8>(W52, p52, g - 393216);
}

// ---------------- fused GEMM + decode ----------------
// Block: 256(M) x 64(N spatial), BK=32. 8 waves = 4(M) x 2(N), wave tile 64x32.
// Pass 1: Ah*Bh on everything. Correction (rows 0..15 only, waves wm==0):
// Ah*Bl + Al*Bh -> full hi/lo precision for the exp rows. 72 MFMA/block-step.
// LDS per buffer (25600 B): [Ah 16K][Al 1K][Bh 4K][Bl 4K]; double buffered = 51200 B.
// NOTE: __launch_bounds__(512,4) — (512,6) capped unified VGPR+AGPR at 80/wave and
// spilled the K-loop live set to scratch (+500 MB HBM traffic, 2x regression, R2).
template<int K, int WD, int HEAD>
DEVI void head_block(const float* __restrict__ F, const u16* __restrict__ Wp,
                     const float* __restrict__ bias, float* __restrict__ out,
                     int bidx, char* smem)
{
  constexpr int S = WD * WD;
  constexpr int NT = (S + 63) / 64;
  constexpr int NSTEP = K / 32;
  constexpr int BUF = 25600;
  constexpr int AL_OFF = 16384, BH_OFF = 17408, BL_OFF = 21504;

  const int b  = bidx / NT;
  const int s0 = (bidx - b * NT) * 64;
  const int tid  = (int)threadIdx.x;
  const int lane = tid & 63;
  const int wv   = tid >> 6;
  const int wm   = wv >> 1;
  const int wn   = wv & 1;
  const int ridx = lane & 15;
  const int kb   = (lane >> 4) << 4;          // k byte offset within row

  const float* Fb   = F + (size_t)b * K * S;
  const int    bs   = (s0 + lane < S) ? s0 + lane : S - 1;
  const float* Fcol = Fb + bs;
  const int    bwr  = (lane * 64 + wv * 8) ^ ((lane & 7) << 4);   // B write byte

  f32x4 acc[4][2];
  #pragma unroll
  for (int i = 0; i < 4; ++i)
    #pragma unroll
    for (int j = 0; j < 2; ++j)
      #pragma unroll
      for (int r = 0; r < 4; ++r) acc[i][j][r] = 0.f;

  char* buf0 = smem;
  char* buf1 = smem + BUF;

  // ---- prologue: stage t=0 into buf0 ----
  {
    const char* g = (const char*)Wp;
    gload_lds16(g + (wv*2+0)*1024 + lane*16, buf0 + (wv*2+0)*1024 + lane*16);
    gload_lds16(g + (wv*2+1)*1024 + lane*16, buf0 + (wv*2+1)*1024 + lane*16);
    if (wv == 0) gload_lds16(g + 16384 + lane*16, buf0 + 16384 + lane*16);
    float bx[4];
    #pragma unroll
    for (int j = 0; j < 4; ++j) bx[j] = Fcol[(size_t)(wv*4 + j) * S];
    u16x4 hv, lv;
    #pragma unroll
    for (int j = 0; j < 4; ++j) { u16 h = f2bf(bx[j]); hv[j] = h; lv[j] = f2bf(bx[j] - bf2f(h)); }
    *(u16x4*)(buf0 + BH_OFF + bwr) = hv;
    *(u16x4*)(buf0 + BL_OFF + bwr) = lv;
  }
  __syncthreads();

  int cur = 0;
  for (int t = 0; t < NSTEP; ++t) {
    char* lc = cur ? buf1 : buf0;
    char* ln = cur ? buf0 : buf1;
    const bool pf = (t + 1 < NSTEP);
    float bx[4];
    if (pf) {
      const char* g = (const char*)Wp + (size_t)(t + 1) * 17408;
      gload_lds16(g + (wv*2+0)*1024 + lane*16, ln + (wv*2+0)*1024 + lane*16);
      gload_lds16(g + (wv*2+1)*1024 + lane*16, ln + (wv*2+1)*1024 + lane*16);
      if (wv == 0) gload_lds16(g + 16384 + lane*16, ln + 16384 + lane*16);
      const float* fc = Fcol + (size_t)(t + 1) * 32 * S;
      #pragma unroll
      for (int j = 0; j < 4; ++j) bx[j] = fc[(size_t)(wv*4 + j) * S];
    }
    // ---- compute from current buffer ----
    s16x8 Ahf[4], Bhf[2];
    #pragma unroll
    for (int mf = 0; mf < 4; ++mf) {
      const int row = wm*64 + mf*16 + ridx;
      Ahf[mf] = *(const s16x8*)(lc + ((row*64 + kb) ^ ((row & 7) << 4)));
    }
    #pragma unroll
    for (int nf = 0; nf < 2; ++nf) {
      const int row = wn*32 + nf*16 + ridx;
      Bhf[nf] = *(const s16x8*)(lc + BH_OFF + ((row*64 + kb) ^ ((row & 7) << 4)));
    }
    #pragma unroll
    for (int mf = 0; mf < 4; ++mf)
      #pragma unroll
      for (int nf = 0; nf < 2; ++nf)
        acc[mf][nf] = __builtin_amdgcn_mfma_f32_16x16x32_bf16(Ahf[mf], Bhf[nf], acc[mf][nf], 0, 0, 0);
    if (wm == 0) {
      const s16x8 Alf = *(const s16x8*)(lc + AL_OFF + ((ridx*64 + kb) ^ ((ridx & 7) << 4)));
      #pragma unroll
      for (int nf = 0; nf < 2; ++nf) {
        const int row = wn*32 + nf*16 + ridx;
        const s16x8 Blf = *(const s16x8*)(lc + BL_OFF + ((row*64 + kb) ^ ((row & 7) << 4)));
        acc[0][nf] = __builtin_amdgcn_mfma_f32_16x16x32_bf16(Ahf[0], Blf, acc[0][nf], 0, 0, 0);
        acc[0][nf] = __builtin_amdgcn_mfma_f32_16x16x32_bf16(Alf, Bhf[nf], acc[0][nf], 0, 0, 0);
      }
    }
    if (pf) {
      u16x4 hv, lv;
      #pragma unroll
      for (int j = 0; j < 4; ++j) { u16 h = f2bf(bx[j]); hv[j] = h; lv[j] = f2bf(bx[j] - bf2f(h)); }
      *(u16x4*)(ln + BH_OFF + bwr) = hv;
      *(u16x4*)(ln + BL_OFF + bwr) = lv;
    }
    __syncthreads();
    cur ^= 1;
  }

  // ---- epilogue: decode + per-anchor LDS transpose + coalesced store ----
  float* ot = (float*)smem;                 // [64][85] floats = 21760 B
  const int vs = (S - s0) < 64 ? (S - s0) : 64;
  for (int a = 0; a < 3; ++a) {
    __syncthreads();
    #pragma unroll
    for (int mf = 0; mf < 4; ++mf) {
      #pragma unroll
      for (int nf = 0; nf < 2; ++nf) {
        const int slc = wn*32 + nf*16 + ridx;
        const int s   = s0 + slc;
        const int hh  = s / WD;
        const int ww  = s - hh * WD;
        #pragma unroll
        for (int r = 0; r < 4; ++r) {
          const int pr = wm*64 + mf*16 + ((lane >> 4) << 2) + r;
          if (pr > 254) continue;
          const int m  = unperm(pr);
          const int am = (m * 772) >> 16;
          if (am != a) continue;
          const int attr = m - 85 * am;
          const float p  = acc[mf][nf][r] + bias[m];
          float val;
          if      (attr == 0) val = ((float)ww + sigm(p)) * (1.0f / WD);
          else if (attr == 1) val = ((float)hh + sigm(p)) * (1.0f / WD);
          else if (attr == 2) val = __expf(p) * anchW<HEAD>(a);
          else if (attr == 3) val = __expf(p) * anchH<HEAD>(a);
          else                val = sigm(p);
          ot[slc * 85 + attr] = val;
        }
      }
    }
    __syncthreads();
    for (int i = tid; i < 64 * 85; i += 512) {
      const int slq = i / 85;
      if (slq < vs)
        out[((size_t)((b * 3 + a) * S) + s0 + slq) * 85 + (i - slq * 85)] = ot[i];
    }
  }
}

__global__ __launch_bounds__(512, 4)
void yolo_fused(const float* __restrict__ f13, const float* __restrict__ f26,
                const float* __restrict__ f52,
                const u16* __restrict__ p13, const float* __restrict__ b13,
                const u16* __restrict__ p26, const float* __restrict__ b26,
                const u16* __restrict__ p52, const float* __restrict__ b52,
                float* __restrict__ out)
{
  __shared__ __attribute__((aligned(16))) char smem[51200];
  const int blk = (int)blockIdx.x;
  float* out13 = out;
  float* out26 = out + 1379040;          // 32*507*85
  float* out52 = out + 6895200;          // + 32*2028*85
  if (blk < 96)        head_block<1024, 13, 0>(f13, p13, b13, out13, blk,       smem);
  else if (blk < 448)  head_block< 512, 26, 1>(f26, p26, b26, out26, blk - 96,  smem);
  else                 head_block< 256, 52, 2>(f52, p52, b52, out52, blk - 448, smem);
}

extern "C" void kernel_launch(void* const* d_in, const int* in_sizes, int n_in,
                              void* d_out, int out_size, void* d_ws, size_t ws_size,
                              hipStream_t stream) {
  (void)in_sizes; (void)n_in; (void)ws_size; (void)out_size;
  const float* f13 = (const float*)d_in[0];
  const float* f26 = (const float*)d_in[1];
  const float* f52 = (const float*)d_in[2];
  const float* W13 = (const float*)d_in[3];
  const float* b13 = (const float*)d_in[4];
  const float* W26 = (const float*)d_in[5];
  const float* b26 = (const float*)d_in[6];
  const float* W52 = (const float*)d_in[7];
  const float* b52 = (const float*)d_in[8];

  u16* p13 = (u16*)d_ws;                 // 32 tiles * 8704 u16
  u16* p26 = p13 + 32 * 8704;            // 16 tiles
  u16* p52 = p26 + 16 * 8704;            //  8 tiles   (total 974848 B)

  pack_all<<<dim3(1792), dim3(256), 0, stream>>>(W13, W26, W52, p13, p26, p52);
  yolo_fused<<<dim3(1824), dim3(512), 0, stream>>>(
      f13, f26, f52, p13, b13, p26, b26, p52, b52, (float*)d_out);
}

// Round 6
// 189.609 us; speedup vs baseline: 1.9790x; 1.2905x over previous
//
#include <hip/hip_runtime.h>
#include <stdint.h>

typedef float  f32x4  __attribute__((ext_vector_type(4)));
typedef short  s16x8  __attribute__((ext_vector_type(8)));
typedef unsigned short u16;
typedef unsigned short u16x2 __attribute__((ext_vector_type(2)));

#define DEVI __device__ __forceinline__

DEVI u16 f2bf(float x) {
  uint32_t u = __float_as_uint(x);
  u += 0x7fffu + ((u >> 16) & 1u);   // RNE to bf16
  return (u16)(u >> 16);
}
DEVI float bf2f(u16 h) { return __uint_as_float(((uint32_t)h) << 16); }
DEVI float sigm(float x) { return 1.0f / (1.0f + __expf(-x)); }

// Row permutation: exp-sensitive rows (attr 2,3 of each anchor: m=2,3,87,88,172,173)
// are placed at permuted rows 0..5 so the hi/lo correction MFMA only touches frag 0.
DEVI int unperm(int pr) {
  if (pr < 6) return 85 * (pr >> 1) + 2 + (pr & 1);
  int idx = pr - 6;
  return idx + (idx < 2 ? 0 : (idx < 85 ? 2 : (idx < 168 ? 4 : 6)));
}

template<int HEAD> DEVI float anchW(int a) {
  if constexpr (HEAD == 0) return a == 0 ? 116.f/416.f : (a == 1 ? 156.f/416.f : 373.f/416.f);
  else if constexpr (HEAD == 1) return a == 0 ? 30.f/416.f : (a == 1 ? 62.f/416.f : 59.f/416.f);
  else return a == 0 ? 10.f/416.f : (a == 1 ? 16.f/416.f : 33.f/416.f);
}
template<int HEAD> DEVI float anchH(int a) {
  if constexpr (HEAD == 0) return a == 0 ? 90.f/416.f : (a == 1 ? 198.f/416.f : 326.f/416.f);
  else if constexpr (HEAD == 1) return a == 0 ? 61.f/416.f : (a == 1 ? 45.f/416.f : 119.f/416.f);
  else return a == 0 ? 13.f/416.f : (a == 1 ? 30.f/416.f : 23.f/416.f);
}

DEVI void gload_lds16(const void* g, void* l) {
  __builtin_amdgcn_global_load_lds((const __attribute__((address_space(1))) void*)g,
                                   (__attribute__((address_space(3))) void*)l, 16, 0, 0);
}

// ---------------- W pre-pack: fp32 -> bf16 (hi plane 256 rows, lo plane rows 0..15),
// row-permuted, XOR-swizzled, tiled per K-step in the exact LDS image.
// Tile layout (17408 B): [Ah 256x32 u16 swz][Al 16x32 u16 swz]
template<int K, int LOGK>
DEVI void pack_head(const float* __restrict__ Wt, u16* __restrict__ dst, int i) {
  const int pr = i >> LOGK;
  const int k  = i & (K - 1);
  float x = 0.f;
  if (pr < 255) x = Wt[(size_t)unperm(pr) * K + k];
  const u16 hi = f2bf(x);
  const int tile = k >> 5;
  const int swz  = (pr * 64 + (k & 31) * 2) ^ ((pr & 7) << 4);
  u16* tb = dst + (size_t)tile * 8704;        // 17408 B per tile
  tb[swz >> 1] = hi;
  if (pr < 16) {
    const u16 lo = f2bf(x - bf2f(hi));
    tb[8192 + (swz >> 1)] = lo;
  }
}

__global__ __launch_bounds__(256)
void pack_all(const float* __restrict__ W13, const float* __restrict__ W26,
              const float* __restrict__ W52, u16* __restrict__ p13,
              u16* __restrict__ p26, u16* __restrict__ p52) {
  const int g = (int)(blockIdx.x * 256 + threadIdx.x);
  if (g < 262144)       pack_head<1024, 10>(W13, p13, g);
  else if (g < 393216)  pack_head< 512,  9>(W26, p26, g - 262144);
  else                  pack_head< 256,  8>(W52, p52, g - 393216);
}

// ---------------- fused GEMM + decode ----------------
// Block: 256(M) x 32(N spatial), BK=32. 8 waves = 4(M) x 2(N), wave tile 64x16.
// acc = 16 regs/lane (not 32): live set ~70-75 regs -> no spill at cap 128,
// occupancy LDS-limited at 3 blocks/CU. (R2/R4 lesson: 256x64 tile = ~120 live
// regs = spill = +80..300 MB scratch HBM traffic.)
// Pass 1: Ah*Bh everywhere. Correction (rows 0..15, waves wm==0): Ah*Bl + Al*Bh.
// LDS per buffer 21504 B: [Ah 16K][Al 1K][Bh 2K][Bl 2K]; dbuf = 43008 B.
template<int K, int WD, int HEAD>
DEVI void head_block(const float* __restrict__ F, const u16* __restrict__ Wp,
                     const float* __restrict__ bias, float* __restrict__ out,
                     int bidx, char* smem)
{
  constexpr int S = WD * WD;
  constexpr int NT = (S + 31) / 32;
  constexpr int NSTEP = K / 32;
  constexpr int BUF = 21504;
  constexpr int AL_OFF = 16384, BH_OFF = 17408, BL_OFF = 19456;

  const int b  = bidx / NT;
  const int s0 = (bidx - b * NT) * 32;
  const int tid  = (int)threadIdx.x;
  const int lane = tid & 63;
  const int wv   = tid >> 6;
  const int wm   = wv >> 1;                   // 0..3 -> channel rows wm*64
  const int wn   = wv & 1;                    // 0..1 -> spatial cols wn*16
  const int ridx = lane & 15;
  const int kb   = (lane >> 4) << 4;          // k byte offset within row

  const float* Fb  = F + (size_t)b * K * S;
  const int    bsl = tid & 31;                // B spatial 0..31
  const int    bk0 = (tid >> 5) << 1;         // B k pair 0,2,..,30
  const int    bs  = (s0 + bsl < S) ? s0 + bsl : S - 1;
  const int    bwr = (bsl * 64 + bk0 * 2) ^ ((bsl & 7) << 4);   // B write byte

  f32x4 acc[4];
  #pragma unroll
  for (int i = 0; i < 4; ++i)
    #pragma unroll
    for (int r = 0; r < 4; ++r) acc[i][r] = 0.f;

  char* buf0 = smem;
  char* buf1 = smem + BUF;

  // ---- prologue: stage t=0 into buf0 ----
  {
    const char* g = (const char*)Wp;
    gload_lds16(g + (wv*2+0)*1024 + lane*16, buf0 + (wv*2+0)*1024 + lane*16);
    gload_lds16(g + (wv*2+1)*1024 + lane*16, buf0 + (wv*2+1)*1024 + lane*16);
    if (wv == 0) gload_lds16(g + 16384 + lane*16, buf0 + 16384 + lane*16);
    const float* fp = Fb + (size_t)bk0 * S + bs;
    float x0 = fp[0], x1 = fp[S];
    u16 h0 = f2bf(x0), h1 = f2bf(x1);
    *(u16x2*)(buf0 + BH_OFF + bwr) = u16x2{h0, h1};
    *(u16x2*)(buf0 + BL_OFF + bwr) = u16x2{f2bf(x0 - bf2f(h0)), f2bf(x1 - bf2f(h1))};
  }
  __syncthreads();

  int cur = 0;
  for (int t = 0; t < NSTEP; ++t) {
    char* lc = cur ? buf1 : buf0;
    char* ln = cur ? buf0 : buf1;
    const bool pf = (t + 1 < NSTEP);
    float x0, x1;
    if (pf) {
      const char* g = (const char*)Wp + (size_t)(t + 1) * 17408;
      gload_lds16(g + (wv*2+0)*1024 + lane*16, ln + (wv*2+0)*1024 + lane*16);
      gload_lds16(g + (wv*2+1)*1024 + lane*16, ln + (wv*2+1)*1024 + lane*16);
      if (wv == 0) gload_lds16(g + 16384 + lane*16, ln + 16384 + lane*16);
      const float* fp = Fb + (size_t)((t + 1) * 32 + bk0) * S + bs;
      x0 = fp[0]; x1 = fp[S];
    }
    // ---- compute from current buffer ----
    s16x8 Ahf[4], Bhf;
    #pragma unroll
    for (int mf = 0; mf < 4; ++mf) {
      const int row = wm*64 + mf*16 + ridx;
      Ahf[mf] = *(const s16x8*)(lc + ((row*64 + kb) ^ ((row & 7) << 4)));
    }
    {
      const int row = wn*16 + ridx;
      Bhf = *(const s16x8*)(lc + BH_OFF + ((row*64 + kb) ^ ((row & 7) << 4)));
    }
    #pragma unroll
    for (int mf = 0; mf < 4; ++mf)
      acc[mf] = __builtin_amdgcn_mfma_f32_16x16x32_bf16(Ahf[mf], Bhf, acc[mf], 0, 0, 0);
    if (wm == 0) {
      const s16x8 Alf = *(const s16x8*)(lc + AL_OFF + ((ridx*64 + kb) ^ ((ridx & 7) << 4)));
      const int row = wn*16 + ridx;
      const s16x8 Blf = *(const s16x8*)(lc + BL_OFF + ((row*64 + kb) ^ ((row & 7) << 4)));
      acc[0] = __builtin_amdgcn_mfma_f32_16x16x32_bf16(Ahf[0], Blf, acc[0], 0, 0, 0);
      acc[0] = __builtin_amdgcn_mfma_f32_16x16x32_bf16(Alf, Bhf, acc[0], 0, 0, 0);
    }
    if (pf) {
      u16 h0 = f2bf(x0), h1 = f2bf(x1);
      *(u16x2*)(ln + BH_OFF + bwr) = u16x2{h0, h1};
      *(u16x2*)(ln + BL_OFF + bwr) = u16x2{f2bf(x0 - bf2f(h0)), f2bf(x1 - bf2f(h1))};
    }
    __syncthreads();
    cur ^= 1;
  }

  // ---- epilogue: decode + per-anchor LDS transpose + coalesced store ----
  float* ot = (float*)smem;                 // [32][85] floats = 10880 B
  const int vs = (S - s0) < 32 ? (S - s0) : 32;
  const int slc = wn*16 + ridx;
  const int s   = s0 + slc;
  const int hh  = s / WD;
  const int ww  = s - hh * WD;
  for (int a = 0; a < 3; ++a) {
    __syncthreads();
    #pragma unroll
    for (int mf = 0; mf < 4; ++mf) {
      #pragma unroll
      for (int r = 0; r < 4; ++r) {
        const int pr = wm*64 + mf*16 + ((lane >> 4) << 2) + r;
        if (pr > 254) continue;
        const int m  = unperm(pr);
        const int am = (m * 772) >> 16;
        if (am != a) continue;
        const int attr = m - 85 * am;
        const float p  = acc[mf][r] + bias[m];
        float val;
        if      (attr == 0) val = ((float)ww + sigm(p)) * (1.0f / WD);
        else if (attr == 1) val = ((float)hh + sigm(p)) * (1.0f / WD);
        else if (attr == 2) val = __expf(p) * anchW<HEAD>(a);
        else if (attr == 3) val = __expf(p) * anchH<HEAD>(a);
        else                val = sigm(p);
        ot[slc * 85 + attr] = val;
      }
    }
    __syncthreads();
    for (int i = tid; i < 32 * 85; i += 512) {
      const int slq = i / 85;
      if (slq < vs)
        out[((size_t)((b * 3 + a) * S) + s0 + slq) * 85 + (i - slq * 85)] = ot[i];
    }
  }
}

__global__ __launch_bounds__(512, 4)
void yolo_fused(const float* __restrict__ f13, const float* __restrict__ f26,
                const float* __restrict__ f52,
                const u16* __restrict__ p13, const float* __restrict__ b13,
                const u16* __restrict__ p26, const float* __restrict__ b26,
                const u16* __restrict__ p52, const float* __restrict__ b52,
                float* __restrict__ out)
{
  __shared__ __attribute__((aligned(16))) char smem[43008];
  const int blk = (int)blockIdx.x;
  float* out13 = out;
  float* out26 = out + 1379040;          // 32*507*85
  float* out52 = out + 6895200;          // + 32*2028*85
  if (blk < 192)       head_block<1024, 13, 0>(f13, p13, b13, out13, blk,       smem);
  else if (blk < 896)  head_block< 512, 26, 1>(f26, p26, b26, out26, blk - 192, smem);
  else                 head_block< 256, 52, 2>(f52, p52, b52, out52, blk - 896, smem);
}

extern "C" void kernel_launch(void* const* d_in, const int* in_sizes, int n_in,
                              void* d_out, int out_size, void* d_ws, size_t ws_size,
                              hipStream_t stream) {
  (void)in_sizes; (void)n_in; (void)ws_size; (void)out_size;
  const float* f13 = (const float*)d_in[0];
  const float* f26 = (const float*)d_in[1];
  const float* f52 = (const float*)d_in[2];
  const float* W13 = (const float*)d_in[3];
  const float* b13 = (const float*)d_in[4];
  const float* W26 = (const float*)d_in[5];
  const float* b26 = (const float*)d_in[6];
  const float* W52 = (const float*)d_in[7];
  const float* b52 = (const float*)d_in[8];

  u16* p13 = (u16*)d_ws;                 // 32 tiles * 8704 u16
  u16* p26 = p13 + 32 * 8704;            // 16 tiles
  u16* p52 = p26 + 16 * 8704;            //  8 tiles   (total 974848 B)

  pack_all<<<dim3(1792), dim3(256), 0, stream>>>(W13, W26, W52, p13, p26, p52);
  // head13 (K=1024): 32 imgs x 6 tiles = 192 blocks; head26: 32x22=704; head52: 32x85=2720.
  yolo_fused<<<dim3(3616), dim3(512), 0, stream>>>(
      f13, f26, f52, p13, b13, p26, b26, p52, b52, (float*)d_out);
}